// Round 1
// baseline (11548.473 us; speedup 1.0000x reference)
//
#include <hip/hip_runtime.h>

#define TT 512
#define BB 256
#define OBS 128
#define LAT 64
#define HID 256
#define SLOT (BB*HID)   // 65536

typedef short bvec8 __attribute__((ext_vector_type(8)));
typedef float fvec4 __attribute__((ext_vector_type(4)));

__device__ __forceinline__ short f2bf(float f){
  union { float f; unsigned u; } v; v.f = f;
  unsigned u = v.u;
  return (short)((u + 0x7FFFu + ((u >> 16) & 1u)) >> 16);
}

__device__ __forceinline__ bvec8 cvt8(const float* __restrict__ p){
  const float4* q = (const float4*)p;
  float4 lo = q[0], hi = q[1];
  bvec8 r;
  r[0] = f2bf(lo.x); r[1] = f2bf(lo.y); r[2] = f2bf(lo.z); r[3] = f2bf(lo.w);
  r[4] = f2bf(hi.x); r[5] = f2bf(hi.y); r[6] = f2bf(hi.z); r[7] = f2bf(hi.w);
  return r;
}

__device__ __forceinline__ fvec4 mfma16(bvec8 a, bvec8 b, fvec4 c){
  return __builtin_amdgcn_mfma_f32_16x16x32_bf16(a, b, c, 0, 0, 0);
}

__global__ void cvt_kernel(const float* __restrict__ src, short* __restrict__ dst, int n){
  int i = blockIdx.x * 256 + threadIdx.x;
  if (i < n) dst[i] = f2bf(src[i]);
}

// Persistent pipelined scan: 128 wgs = 8 groups (32 samples each) x 16 wgs.
// Iteration i: waves0-1: h_i = GRU(h_{i-1}, x_i) (16 h-cols/wg);
//              waves2-3: u_{i-1} = relu([h_{i-1},z_{i-2}] @ pW1^T) (16 u-cols/wg);
//              all waves: post_{i-2} = u_{i-2} @ pW2^T (full, replicated) -> z_{i-2}.
// One group barrier per iteration.
__global__ __launch_bounds__(256) void scan_kernel(
    const float* __restrict__ x, const float* __restrict__ eps,
    const float* __restrict__ b_ih, const float* __restrict__ b_hh,
    const float* __restrict__ pb1, const float* __restrict__ pb2,
    const short* __restrict__ Whh, const short* __restrict__ Wih,
    const short* __restrict__ Pw1, const short* __restrict__ Pw2,
    short* __restrict__ z_all, float* __restrict__ hbuf, short* __restrict__ ubuf,
    float* __restrict__ post_mean, float* __restrict__ post_logvar,
    unsigned* __restrict__ bars)
{
  const int tid  = threadIdx.x;
  const int wave = tid >> 6;
  const int lane = tid & 63;
  const int quad = lane >> 4;
  const int nl   = lane & 15;
  const int g    = blockIdx.x >> 4;   // group 0..7
  const int s    = blockIdx.x & 15;   // slice 0..15
  const int b0   = g * 32;

  __shared__ __align__(16) short wA[3*12*64*8];   // [gate][kstep][lane][8] frag-order
  __shared__ float Cex[2][8][16][20];             // post exchange, padded
  __shared__ __align__(16) short zbuf[32][72];    // z_{i-2} bf16, padded stride
  __shared__ float bias_r[16], bias_z[16], bias_nx[16], bias_nh[16], pb1s[16], pb2s[128];

  if (tid < 16){
    int j = 16*s + tid;
    bias_r[tid]  = b_ih[j]       + b_hh[j];
    bias_z[tid]  = b_ih[256 + j] + b_hh[256 + j];
    bias_nx[tid] = b_ih[512 + j];
    bias_nh[tid] = b_hh[512 + j];
    pb1s[tid]    = pb1[j];
  }
  if (tid < 128) pb2s[tid] = pb2[tid];
  // stage W_hh/W_ih slices into LDS in exact B-fragment order (conflict-free reads)
  for (int slot = tid; slot < 3*12*64; slot += 256){
    int ln   = slot & 63;
    int ks   = (slot >> 6) % 12;
    int gate = slot / (12*64);
    int grow = gate*256 + 16*s + (ln & 15);
    int k    = ks*32 + (ln >> 4)*8;
    bvec8 v;
    if (ks < 8) v = *(const bvec8*)(Whh + grow*256 + k);
    else        v = *(const bvec8*)(Wih + grow*128 + (k - 256));
    *(bvec8*)(wA + slot*8) = v;
  }
  __syncthreads();

  unsigned* cnt = bars + g*64;
  unsigned* gen = bars + g*64 + 32;

  for (int i = 0; i < TT + 2; ++i){
    const float* h_prev = hbuf + ((i+1)&1)*SLOT;
    float*       h_cur  = hbuf + (i&1)*SLOT;
    const short* u_old  = ubuf + (i&1)*SLOT;        // u_{i-2}
    short*       u_new  = ubuf + ((i+1)&1)*SLOT;    // u_{i-1}

    // ---------------- (c) post & z for j2 = i-2 (all waves, full N=128) -------------
    if (i >= 2){
      fvec4 a00 = (fvec4)0.0f, a01 = (fvec4)0.0f, a10 = (fvec4)0.0f, a11 = (fvec4)0.0f;
      const short* u0r = u_old + (b0 + nl)*HID;
      const short* u1r = u_old + (b0 + 16 + nl)*HID;
      const int n0 = (2*wave)*16 + nl;
      for (int ks = 0; ks < 8; ++ks){
        int ko = ks*32 + quad*8;
        bvec8 af0 = *(const bvec8*)(u0r + ko);
        bvec8 af1 = *(const bvec8*)(u1r + ko);
        bvec8 bw0 = *(const bvec8*)(Pw2 + n0*HID + ko);
        bvec8 bw1 = *(const bvec8*)(Pw2 + (n0+16)*HID + ko);
        a00 = mfma16(af0, bw0, a00);
        a10 = mfma16(af1, bw0, a10);
        a01 = mfma16(af0, bw1, a01);
        a11 = mfma16(af1, bw1, a11);
      }
      for (int r = 0; r < 4; ++r){
        Cex[0][2*wave  ][quad*4+r][nl] = a00[r];
        Cex[0][2*wave+1][quad*4+r][nl] = a01[r];
        Cex[1][2*wave  ][quad*4+r][nl] = a10[r];
        Cex[1][2*wave+1][quad*4+r][nl] = a11[r];
      }
    }
    __syncthreads();
    if (i >= 2){
      const int j2 = i - 2;
      for (int rr = 0; rr < 8; ++rr){
        int idx = tid + 256*rr;          // 0..2047 -> (m,l)
        int m = idx >> 6, l = idx & 63;
        float mean = Cex[m>>4][l>>4][m&15][l&15] + pb2s[l];
        float lv   = Cex[m>>4][4 + (l>>4)][m&15][l&15] + pb2s[64 + l];
        float ep   = eps[((size_t)j2*BB + b0 + m)*LAT + l];
        float zv   = mean + ep * __expf(0.5f*lv);
        short zb   = f2bf(zv);
        zbuf[m][l] = zb;
        size_t orow = (size_t)j2*BB + b0 + m;
        if ((l >> 2) == s)       z_all[orow*LAT + l]       = zb;
        if ((l >> 3) == s)       post_mean[orow*LAT + l]   = mean;
        if ((l >> 3) + 8 == s)   post_logvar[orow*LAT + l] = lv;
      }
    } else {
      for (int idx = tid; idx < 2048; idx += 256) zbuf[idx >> 6][idx & 63] = 0;
    }
    __syncthreads();

    // ------------- (a) GRU step i (waves 0,1) | (b) u_{i-1} (waves 2,3) -------------
    if (wave < 2){
      if (i < TT){
        const int Mt = wave;
        fvec4 ar = (fvec4)0.0f, az = (fvec4)0.0f, anh = (fvec4)0.0f, anx = (fvec4)0.0f;
        const float* hp = h_prev + (b0 + Mt*16 + nl)*HID;
        const float* xp = x + ((size_t)i*BB + b0 + Mt*16 + nl)*OBS;
        for (int ks = 0; ks < 12; ++ks){
          if (i == 0 && ks < 8) continue;       // h_{-1} = 0
          bvec8 a = (ks < 8) ? cvt8(hp + ks*32 + quad*8)
                             : cvt8(xp + (ks-8)*32 + quad*8);
          bvec8 br = *(const bvec8*)(wA + ((0*12 + ks)*64 + lane)*8);
          bvec8 bz = *(const bvec8*)(wA + ((1*12 + ks)*64 + lane)*8);
          bvec8 bn = *(const bvec8*)(wA + ((2*12 + ks)*64 + lane)*8);
          ar = mfma16(a, br, ar);
          az = mfma16(a, bz, az);
          if (ks < 8) anh = mfma16(a, bn, anh);
          else        anx = mfma16(a, bn, anx);
        }
        const int j = 16*s + nl;
        for (int r = 0; r < 4; ++r){
          int b = b0 + Mt*16 + quad*4 + r;
          float hprev_v = (i == 0) ? 0.0f : h_prev[b*HID + j];
          float rg = 1.0f/(1.0f + __expf(-(ar[r] + bias_r[nl])));
          float zg = 1.0f/(1.0f + __expf(-(az[r] + bias_z[nl])));
          float ng = tanhf(anx[r] + bias_nx[nl] + rg*(anh[r] + bias_nh[nl]));
          h_cur[b*HID + j] = (1.0f - zg)*ng + zg*hprev_v;
        }
      }
    } else {
      if (i >= 1 && i <= TT){
        const int Mt = wave - 2;
        fvec4 au = (fvec4)0.0f;
        const float* hp = h_prev + (b0 + Mt*16 + nl)*HID;
        const int un = 16*s + nl;
        for (int ks = 0; ks < 10; ++ks){
          bvec8 a;
          if (ks < 8) a = cvt8(hp + ks*32 + quad*8);
          else        a = *(const bvec8*)(&zbuf[Mt*16 + nl][(ks-8)*32 + quad*8]);
          bvec8 bw = *(const bvec8*)(Pw1 + un*320 + ks*32 + quad*8);
          au = mfma16(a, bw, au);
        }
        for (int r = 0; r < 4; ++r){
          int b = b0 + Mt*16 + quad*4 + r;
          float uv = au[r] + pb1s[nl];
          u_new[b*HID + un] = f2bf(uv > 0.0f ? uv : 0.0f);
        }
      }
    }

    // ---------------- group barrier (16 wgs) ----------------
    __syncthreads();
    if (tid == 0){
      unsigned old_gen = __hip_atomic_load(gen, __ATOMIC_RELAXED, __HIP_MEMORY_SCOPE_AGENT);
      __threadfence();
      unsigned arrived = __hip_atomic_fetch_add(cnt, 1u, __ATOMIC_ACQ_REL, __HIP_MEMORY_SCOPE_AGENT);
      if (arrived == 15u){
        __hip_atomic_store(cnt, 0u, __ATOMIC_RELAXED, __HIP_MEMORY_SCOPE_AGENT);
        __hip_atomic_fetch_add(gen, 1u, __ATOMIC_RELEASE, __HIP_MEMORY_SCOPE_AGENT);
      } else {
        while (__hip_atomic_load(gen, __ATOMIC_RELAXED, __HIP_MEMORY_SCOPE_AGENT) == old_gen)
          __builtin_amdgcn_s_sleep(1);
      }
      __threadfence();
    }
    __syncthreads();
  }
}

// Tail: prior (from z_{t-1}) and decoder (from z_t), fully parallel over (p,t,mblk).
__global__ __launch_bounds__(256) void tail_kernel(
    const short* __restrict__ z_all,
    const short* __restrict__ Tw1, const short* __restrict__ Tw2,
    const short* __restrict__ Dw1, const short* __restrict__ Dw2,
    const float* __restrict__ tb1, const float* __restrict__ tb2,
    const float* __restrict__ db1, const float* __restrict__ db2,
    float* __restrict__ prior_mean, float* __restrict__ prior_logvar,
    float* __restrict__ recons)
{
  const int tid  = threadIdx.x;
  const int wave = tid >> 6;
  const int lane = tid & 63;
  const int quad = lane >> 4;
  const int nl   = lane & 15;
  const int wg   = blockIdx.x;
  const int p    = wg >> 11;        // 0 = prior, 1 = decoder
  const int t    = (wg >> 2) & 511;
  const int mb   = wg & 3;          // 64-sample block

  const short* W1 = p ? Dw1 : Tw1;
  const short* W2 = p ? Dw2 : Tw2;
  const float* B1 = p ? db1 : tb1;
  const float* B2 = p ? db2 : tb2;

  __shared__ __align__(16) short u1[64][264];
  __shared__ float b1s[HID], b2s[OBS];

  b1s[tid] = B1[tid];
  if (tid < OBS) b2s[tid] = B2[tid];
  __syncthreads();

  const bool zzero = (p == 0 && t == 0);
  const int  tz    = p ? t : (t - 1);
  const short* zsrc = z_all + (((size_t)(zzero ? 0 : tz))*BB + mb*64)*LAT;

  // layer 1: M=64, N=256, K=64
  fvec4 acc1[4][4];
  for (int a = 0; a < 4; ++a) for (int b = 0; b < 4; ++b) acc1[a][b] = (fvec4)0.0f;
  for (int ks = 0; ks < 2; ++ks){
    bvec8 af[4];
    for (int mt = 0; mt < 4; ++mt){
      if (zzero) af[mt] = (bvec8)(short)0;
      else af[mt] = *(const bvec8*)(zsrc + (mt*16 + nl)*LAT + ks*32 + quad*8);
    }
    for (int nt = 0; nt < 4; ++nt){
      int n = (wave*4 + nt)*16 + nl;
      bvec8 bw = *(const bvec8*)(W1 + n*LAT + ks*32 + quad*8);
      for (int mt = 0; mt < 4; ++mt) acc1[mt][nt] = mfma16(af[mt], bw, acc1[mt][nt]);
    }
  }
  for (int nt = 0; nt < 4; ++nt){
    int n = (wave*4 + nt)*16 + nl;
    float bias = b1s[n];
    for (int mt = 0; mt < 4; ++mt)
      for (int r = 0; r < 4; ++r){
        float v = acc1[mt][nt][r] + bias;
        u1[mt*16 + quad*4 + r][n] = f2bf(v > 0.0f ? v : 0.0f);
      }
  }
  __syncthreads();

  // layer 2: M=64, N=128, K=256
  fvec4 acc2[4][2];
  for (int a = 0; a < 4; ++a) for (int b = 0; b < 2; ++b) acc2[a][b] = (fvec4)0.0f;
  for (int ks = 0; ks < 8; ++ks){
    bvec8 af[4];
    for (int mt = 0; mt < 4; ++mt)
      af[mt] = *(const bvec8*)(&u1[mt*16 + nl][ks*32 + quad*8]);
    for (int nt = 0; nt < 2; ++nt){
      int n = (wave*2 + nt)*16 + nl;
      bvec8 bw = *(const bvec8*)(W2 + n*HID + ks*32 + quad*8);
      for (int mt = 0; mt < 4; ++mt) acc2[mt][nt] = mfma16(af[mt], bw, acc2[mt][nt]);
    }
  }
  for (int nt = 0; nt < 2; ++nt){
    int n = (wave*2 + nt)*16 + nl;
    float bias = b2s[n];
    for (int mt = 0; mt < 4; ++mt)
      for (int r = 0; r < 4; ++r){
        int b = mb*64 + mt*16 + quad*4 + r;
        size_t row = (size_t)t*BB + b;
        float v = acc2[mt][nt][r] + bias;
        if (p) recons[row*OBS + n] = v;
        else if (n < LAT) prior_mean[row*LAT + n] = v;
        else              prior_logvar[row*LAT + (n - LAT)] = v;
      }
  }
}

extern "C" void kernel_launch(void* const* d_in, const int* in_sizes, int n_in,
                              void* d_out, int out_size, void* d_ws, size_t ws_size,
                              hipStream_t stream) {
  const float* x    = (const float*)d_in[0];
  const float* eps  = (const float*)d_in[1];
  const float* W_ih = (const float*)d_in[2];
  const float* W_hh = (const float*)d_in[3];
  const float* b_ih = (const float*)d_in[4];
  const float* b_hh = (const float*)d_in[5];
  const float* tW1  = (const float*)d_in[6];
  const float* tb1  = (const float*)d_in[7];
  const float* tW2  = (const float*)d_in[8];
  const float* tb2  = (const float*)d_in[9];
  const float* pW1  = (const float*)d_in[10];
  const float* pb1  = (const float*)d_in[11];
  const float* pW2  = (const float*)d_in[12];
  const float* pb2  = (const float*)d_in[13];
  const float* dW1  = (const float*)d_in[14];
  const float* db1  = (const float*)d_in[15];
  const float* dW2  = (const float*)d_in[16];
  const float* db2  = (const float*)d_in[17];

  float* out          = (float*)d_out;
  float* recons       = out;                 // 512*256*128
  float* prior_mean   = out + 16777216;      // 512*256*64
  float* prior_logvar = out + 25165824;
  float* post_mean    = out + 33554432;
  float* post_logvar  = out + 41943040;

  char* ws = (char*)d_ws;
  short* z_all = (short*)ws;                               // bf16, 16,777,216 B
  float* hbuf  = (float*)(ws + 16777216);                  // 524,288 B
  short* ubuf  = (short*)(ws + 16777216 + 524288);         // 262,144 B
  short* wts   = (short*)(ws + 16777216 + 524288 + 262144);
  short* Whh = wts;
  short* Wih = Whh + 196608;
  short* Pw1 = Wih + 98304;
  short* Pw2 = Pw1 + 81920;
  short* Tw1 = Pw2 + 32768;
  short* Tw2 = Tw1 + 16384;
  short* Dw1 = Tw2 + 32768;
  short* Dw2 = Dw1 + 16384;
  unsigned* bars = (unsigned*)(Dw2 + 32768);

  hipMemsetAsync(bars, 0, 4096, stream);
  cvt_kernel<<<(196608+255)/256, 256, 0, stream>>>(W_hh, Whh, 196608);
  cvt_kernel<<<( 98304+255)/256, 256, 0, stream>>>(W_ih, Wih,  98304);
  cvt_kernel<<<( 81920+255)/256, 256, 0, stream>>>(pW1,  Pw1,  81920);
  cvt_kernel<<<( 32768+255)/256, 256, 0, stream>>>(pW2,  Pw2,  32768);
  cvt_kernel<<<( 16384+255)/256, 256, 0, stream>>>(tW1,  Tw1,  16384);
  cvt_kernel<<<( 32768+255)/256, 256, 0, stream>>>(tW2,  Tw2,  32768);
  cvt_kernel<<<( 16384+255)/256, 256, 0, stream>>>(dW1,  Dw1,  16384);
  cvt_kernel<<<( 32768+255)/256, 256, 0, stream>>>(dW2,  Dw2,  32768);

  scan_kernel<<<128, 256, 0, stream>>>(x, eps, b_ih, b_hh, pb1, pb2,
                                       Whh, Wih, Pw1, Pw2,
                                       z_all, hbuf, ubuf, post_mean, post_logvar, bars);
  tail_kernel<<<4096, 256, 0, stream>>>(z_all, Tw1, Tw2, Dw1, Dw2,
                                        tb1, tb2, db1, db2,
                                        prior_mean, prior_logvar, recons);
}

// Round 2
// 6303.698 us; speedup vs baseline: 1.8320x; 1.8320x over previous
//
#include <hip/hip_runtime.h>

#define TT 512
#define BB 256
#define OBS 128
#define LAT 64
#define HID 256

typedef short bvec8 __attribute__((ext_vector_type(8)));
typedef float fvec4 __attribute__((ext_vector_type(4)));

__device__ __forceinline__ short f2bf(float f){
  union { float f; unsigned u; } v; v.f = f;
  unsigned u = v.u;
  return (short)((u + 0x7FFFu + ((u >> 16) & 1u)) >> 16);
}

__device__ __forceinline__ bvec8 cvt8(const float* __restrict__ p){
  const float4* q = (const float4*)p;
  float4 lo = q[0], hi = q[1];
  bvec8 r;
  r[0] = f2bf(lo.x); r[1] = f2bf(lo.y); r[2] = f2bf(lo.z); r[3] = f2bf(lo.w);
  r[4] = f2bf(hi.x); r[5] = f2bf(hi.y); r[6] = f2bf(hi.z); r[7] = f2bf(hi.w);
  return r;
}

__device__ __forceinline__ bvec8 cvt8r(float4 lo, float4 hi){
  bvec8 r;
  r[0] = f2bf(lo.x); r[1] = f2bf(lo.y); r[2] = f2bf(lo.z); r[3] = f2bf(lo.w);
  r[4] = f2bf(hi.x); r[5] = f2bf(hi.y); r[6] = f2bf(hi.z); r[7] = f2bf(hi.w);
  return r;
}

__device__ __forceinline__ fvec4 mfma16(bvec8 a, bvec8 b, fvec4 c){
  return __builtin_amdgcn_mfma_f32_16x16x32_bf16(a, b, c, 0, 0, 0);
}

__global__ void cvt_kernel(const float* __restrict__ src, short* __restrict__ dst, int n){
  int i = blockIdx.x * 256 + threadIdx.x;
  if (i < n) dst[i] = f2bf(src[i]);
}

// ---------------------------------------------------------------------------
// GRU scan: 16 wgs x 512 threads; wg g owns samples [16g, 16g+16).
// Wave w (0..7) owns gate-columns j in [32w, 32w+32) of each gate (r,z,n).
// All weights live in registers as MFMA B-fragments. h fp32 lives in registers
// (static lane ownership); bf16 A-frag copy double-buffered in LDS.
// One __syncthreads per step. No inter-wg communication.
// ---------------------------------------------------------------------------
__global__ __launch_bounds__(512, 2) void gru_kernel(
    const float* __restrict__ x,
    const float* __restrict__ W_ih, const float* __restrict__ W_hh,
    const float* __restrict__ b_ih, const float* __restrict__ b_hh,
    short* __restrict__ h_all)
{
  const int tid  = threadIdx.x;
  const int wave = tid >> 6;
  const int lane = tid & 63;
  const int quad = lane >> 4;
  const int nl   = lane & 15;
  const int b0   = blockIdx.x * 16;

  __shared__ __align__(16) short hA[2][16][264];

  // ---- load weights into registers (B-frag layout: n=nl, k=quad*8+idx) ----
  bvec8 Whr[8][2], Whz[8][2], Whn[8][2];
  bvec8 Wxr[4][2], Wxz[4][2], Wxn[4][2];
  float br[2], bz[2], bnx[2], bnh[2];
#pragma unroll
  for (int nt = 0; nt < 2; ++nt){
    const int j = wave*32 + nt*16 + nl;
#pragma unroll
    for (int ks = 0; ks < 8; ++ks){
      const int k = ks*32 + quad*8;
      Whr[ks][nt] = cvt8(W_hh + (0*HID + j)*HID + k);
      Whz[ks][nt] = cvt8(W_hh + (1*HID + j)*HID + k);
      Whn[ks][nt] = cvt8(W_hh + (2*HID + j)*HID + k);
    }
#pragma unroll
    for (int ks = 0; ks < 4; ++ks){
      const int k = ks*32 + quad*8;
      Wxr[ks][nt] = cvt8(W_ih + (0*HID + j)*OBS + k);
      Wxz[ks][nt] = cvt8(W_ih + (1*HID + j)*OBS + k);
      Wxn[ks][nt] = cvt8(W_ih + (2*HID + j)*OBS + k);
    }
    br[nt]  = b_ih[j]       + b_hh[j];
    bz[nt]  = b_ih[HID + j] + b_hh[HID + j];
    bnx[nt] = b_ih[2*HID + j];
    bnh[nt] = b_hh[2*HID + j];
  }

  float hreg[2][4];
#pragma unroll
  for (int nt = 0; nt < 2; ++nt)
#pragma unroll
    for (int r = 0; r < 4; ++r) hreg[nt][r] = 0.0f;

  // prefetch x for step 0 (A-frag: m=nl, k=quad*8+idx)
  float4 xr8[8];
#pragma unroll
  for (int ks = 0; ks < 4; ++ks){
    const float* xp = x + ((size_t)0*BB + b0 + nl)*OBS + ks*32 + quad*8;
    xr8[2*ks]   = ((const float4*)xp)[0];
    xr8[2*ks+1] = ((const float4*)xp)[1];
  }

  const int orow = tid >> 5;    // 0..15
  const int oseg = tid & 31;    // 0..31

  for (int i = 0; i < TT; ++i){
    // write out h_{i-1} (coalesced, from LDS buffer finalized last step)
    if (i > 0){
      bvec8 v = *(const bvec8*)&hA[i&1][orow][oseg*8];
      *(bvec8*)(h_all + ((size_t)(i-1)*BB + b0 + orow)*HID + oseg*8) = v;
    }

    fvec4 ar[2], az[2], anh_[2], anx[2];
#pragma unroll
    for (int nt = 0; nt < 2; ++nt){
      ar[nt] = (fvec4)0.0f; az[nt] = (fvec4)0.0f;
      anh_[nt] = (fvec4)0.0f; anx[nt] = (fvec4)0.0f;
    }

    // h-part MFMAs (K=256)
    if (i > 0){
#pragma unroll
      for (int ks = 0; ks < 8; ++ks){
        bvec8 a = *(const bvec8*)&hA[i&1][nl][ks*32 + quad*8];
#pragma unroll
        for (int nt = 0; nt < 2; ++nt){
          ar[nt]   = mfma16(a, Whr[ks][nt], ar[nt]);
          az[nt]   = mfma16(a, Whz[ks][nt], az[nt]);
          anh_[nt] = mfma16(a, Whn[ks][nt], anh_[nt]);
        }
      }
    }
    // x-part MFMAs (K=128)
#pragma unroll
    for (int ks = 0; ks < 4; ++ks){
      bvec8 a = cvt8r(xr8[2*ks], xr8[2*ks+1]);
#pragma unroll
      for (int nt = 0; nt < 2; ++nt){
        ar[nt]  = mfma16(a, Wxr[ks][nt], ar[nt]);
        az[nt]  = mfma16(a, Wxz[ks][nt], az[nt]);
        anx[nt] = mfma16(a, Wxn[ks][nt], anx[nt]);
      }
    }
    // prefetch x for next step
    if (i + 1 < TT){
#pragma unroll
      for (int ks = 0; ks < 4; ++ks){
        const float* xp = x + ((size_t)(i+1)*BB + b0 + nl)*OBS + ks*32 + quad*8;
        xr8[2*ks]   = ((const float4*)xp)[0];
        xr8[2*ks+1] = ((const float4*)xp)[1];
      }
    }
    // gate math (C-layout: m = quad*4+r, j = wave*32 + nt*16 + nl)
#pragma unroll
    for (int nt = 0; nt < 2; ++nt){
      const int j = wave*32 + nt*16 + nl;
#pragma unroll
      for (int r = 0; r < 4; ++r){
        float rg = 1.0f/(1.0f + __expf(-(ar[nt][r] + br[nt])));
        float zg = 1.0f/(1.0f + __expf(-(az[nt][r] + bz[nt])));
        float ng = tanhf(anx[nt][r] + bnx[nt] + rg*(anh_[nt][r] + bnh[nt]));
        float hn = (1.0f - zg)*ng + zg*hreg[nt][r];
        hreg[nt][r] = hn;
        hA[(i+1)&1][quad*4 + r][j] = f2bf(hn);
      }
    }
    __syncthreads();
  }
  // epilogue: write h_{TT-1}  (TT even -> buffer 0)
  {
    bvec8 v = *(const bvec8*)&hA[TT&1][orow][oseg*8];
    *(bvec8*)(h_all + ((size_t)(TT-1)*BB + b0 + orow)*HID + oseg*8) = v;
  }
}

// ---------------------------------------------------------------------------
// z scan: 16 wgs x 256 threads; wg g owns samples [16g, 16g+16).
// Per step: u = relu(h_t @ pW1h^T + z_prev @ pW1z^T + pb1);
//           post = u @ pW2^T + pb2; z = mean + eps*exp(0.5*logvar).
// Weights in registers; h-frags prefetched from global; 3 barriers/step.
// ---------------------------------------------------------------------------
__global__ __launch_bounds__(256, 1) void zscan_kernel(
    const short* __restrict__ h_all, const float* __restrict__ eps,
    const short* __restrict__ Pw1, const short* __restrict__ Pw2,
    const float* __restrict__ pb1, const float* __restrict__ pb2,
    short* __restrict__ z_all,
    float* __restrict__ post_mean, float* __restrict__ post_logvar)
{
  const int tid  = threadIdx.x;
  const int wave = tid >> 6;
  const int lane = tid & 63;
  const int quad = lane >> 4;
  const int nl   = lane & 15;
  const int b0   = blockIdx.x * 16;

  __shared__ __align__(16) short zA[2][16][72];
  __shared__ __align__(16) short uA[16][264];
  __shared__ float postL[16][132];

  // weights (B-frag layout). pW1 is [256][320]: k<256 = h-part, k>=256 = z-part.
  bvec8 W1h[8][4], W1z[2][4], W2[8][2];
  float pb1r[4];
#pragma unroll
  for (int nt = 0; nt < 4; ++nt){
    const int n = wave*64 + nt*16 + nl;
#pragma unroll
    for (int ks = 0; ks < 8; ++ks)
      W1h[ks][nt] = *(const bvec8*)(Pw1 + n*320 + ks*32 + quad*8);
#pragma unroll
    for (int ks = 0; ks < 2; ++ks)
      W1z[ks][nt] = *(const bvec8*)(Pw1 + n*320 + 256 + ks*32 + quad*8);
    pb1r[nt] = pb1[n];
  }
#pragma unroll
  for (int nt = 0; nt < 2; ++nt){
    const int n = wave*32 + nt*16 + nl;
#pragma unroll
    for (int ks = 0; ks < 8; ++ks)
      W2[ks][nt] = *(const bvec8*)(Pw2 + n*HID + ks*32 + quad*8);
  }

  // z-math constants per thread (4 latent cols each)
  const int zm  = tid >> 4;         // sample row 0..15
  const int zl  = (tid & 15) * 4;   // latent col base
  float4 pb2m = *(const float4*)(pb2 + zl);
  float4 pb2v = *(const float4*)(pb2 + 64 + zl);

  // prefetch h-frags + eps for step 0
  bvec8 hf[8];
#pragma unroll
  for (int ks = 0; ks < 8; ++ks)
    hf[ks] = *(const bvec8*)(h_all + ((size_t)0*BB + b0 + nl)*HID + ks*32 + quad*8);
  float4 ef = *(const float4*)(eps + ((size_t)0*BB + b0 + zm)*LAT + zl);

  for (int i = 0; i < TT; ++i){
    // ---- stage pin: u accumulation ----
    fvec4 au[4];
#pragma unroll
    for (int nt = 0; nt < 4; ++nt) au[nt] = (fvec4)0.0f;
#pragma unroll
    for (int ks = 0; ks < 8; ++ks){
      bvec8 a = hf[ks];
#pragma unroll
      for (int nt = 0; nt < 4; ++nt) au[nt] = mfma16(a, W1h[ks][nt], au[nt]);
    }
    if (i > 0){
#pragma unroll
      for (int ks = 0; ks < 2; ++ks){
        bvec8 a = *(const bvec8*)&zA[i&1][nl][ks*32 + quad*8];
#pragma unroll
        for (int nt = 0; nt < 4; ++nt) au[nt] = mfma16(a, W1z[ks][nt], au[nt]);
      }
    }
    // prefetch h for next step
    if (i + 1 < TT){
#pragma unroll
      for (int ks = 0; ks < 8; ++ks)
        hf[ks] = *(const bvec8*)(h_all + ((size_t)(i+1)*BB + b0 + nl)*HID + ks*32 + quad*8);
    }
    // u = relu(au + pb1) -> uA
#pragma unroll
    for (int nt = 0; nt < 4; ++nt){
      const int n = wave*64 + nt*16 + nl;
#pragma unroll
      for (int r = 0; r < 4; ++r){
        float u = au[nt][r] + pb1r[nt];
        uA[quad*4 + r][n] = f2bf(u > 0.0f ? u : 0.0f);
      }
    }
    __syncthreads();

    // ---- stage B: post = u @ pW2^T ----
    fvec4 ap[2];
#pragma unroll
    for (int nt = 0; nt < 2; ++nt) ap[nt] = (fvec4)0.0f;
#pragma unroll
    for (int ks = 0; ks < 8; ++ks){
      bvec8 a = *(const bvec8*)&uA[nl][ks*32 + quad*8];
#pragma unroll
      for (int nt = 0; nt < 2; ++nt) ap[nt] = mfma16(a, W2[ks][nt], ap[nt]);
    }
#pragma unroll
    for (int nt = 0; nt < 2; ++nt){
      const int n = wave*32 + nt*16 + nl;
#pragma unroll
      for (int r = 0; r < 4; ++r) postL[quad*4 + r][n] = ap[nt][r];
    }
    __syncthreads();

    // ---- z math ----
    {
      float4 mean, lv;
      mean.x = postL[zm][zl+0] + pb2m.x;  lv.x = postL[zm][64+zl+0] + pb2v.x;
      mean.y = postL[zm][zl+1] + pb2m.y;  lv.y = postL[zm][64+zl+1] + pb2v.y;
      mean.z = postL[zm][zl+2] + pb2m.z;  lv.z = postL[zm][64+zl+2] + pb2v.z;
      mean.w = postL[zm][zl+3] + pb2m.w;  lv.w = postL[zm][64+zl+3] + pb2v.w;
      float z0 = mean.x + ef.x * __expf(0.5f*lv.x);
      float z1 = mean.y + ef.y * __expf(0.5f*lv.y);
      float z2 = mean.z + ef.z * __expf(0.5f*lv.z);
      float z3 = mean.w + ef.w * __expf(0.5f*lv.w);
      size_t orow = ((size_t)i*BB + b0 + zm)*LAT + zl;
      short4 zb; zb.x = f2bf(z0); zb.y = f2bf(z1); zb.z = f2bf(z2); zb.w = f2bf(z3);
      *(short4*)(z_all + orow) = zb;
      *(float4*)(post_mean + orow)   = mean;
      *(float4*)(post_logvar + orow) = lv;
      *(short4*)&zA[(i+1)&1][zm][zl] = zb;
      if (i + 1 < TT)
        ef = *(const float4*)(eps + ((size_t)(i+1)*BB + b0 + zm)*LAT + zl);
    }
    __syncthreads();
  }
}

// ---------------------------------------------------------------------------
// Tail: prior (from z_{t-1}) and decoder (from z_t), parallel over (p,t,mblk).
// ---------------------------------------------------------------------------
__global__ __launch_bounds__(256) void tail_kernel(
    const short* __restrict__ z_all,
    const short* __restrict__ Tw1, const short* __restrict__ Tw2,
    const short* __restrict__ Dw1, const short* __restrict__ Dw2,
    const float* __restrict__ tb1, const float* __restrict__ tb2,
    const float* __restrict__ db1, const float* __restrict__ db2,
    float* __restrict__ prior_mean, float* __restrict__ prior_logvar,
    float* __restrict__ recons)
{
  const int tid  = threadIdx.x;
  const int wave = tid >> 6;
  const int lane = tid & 63;
  const int quad = lane >> 4;
  const int nl   = lane & 15;
  const int wg   = blockIdx.x;
  const int p    = wg >> 11;        // 0 = prior, 1 = decoder
  const int t    = (wg >> 2) & 511;
  const int mb   = wg & 3;          // 64-sample block

  const short* W1 = p ? Dw1 : Tw1;
  const short* W2 = p ? Dw2 : Tw2;
  const float* B1 = p ? db1 : tb1;
  const float* B2 = p ? db2 : tb2;

  __shared__ __align__(16) short u1[64][264];
  __shared__ float b1s[HID], b2s[OBS];

  b1s[tid] = B1[tid];
  if (tid < OBS) b2s[tid] = B2[tid];
  __syncthreads();

  const bool zzero = (p == 0 && t == 0);
  const int  tz    = p ? t : (t - 1);
  const short* zsrc = z_all + (((size_t)(zzero ? 0 : tz))*BB + mb*64)*LAT;

  // layer 1: M=64, N=256, K=64
  fvec4 acc1[4][4];
  for (int a = 0; a < 4; ++a) for (int b = 0; b < 4; ++b) acc1[a][b] = (fvec4)0.0f;
  for (int ks = 0; ks < 2; ++ks){
    bvec8 af[4];
    for (int mt = 0; mt < 4; ++mt){
      if (zzero) af[mt] = (bvec8)(short)0;
      else af[mt] = *(const bvec8*)(zsrc + (mt*16 + nl)*LAT + ks*32 + quad*8);
    }
    for (int nt = 0; nt < 4; ++nt){
      int n = (wave*4 + nt)*16 + nl;
      bvec8 bw = *(const bvec8*)(W1 + n*LAT + ks*32 + quad*8);
      for (int mt = 0; mt < 4; ++mt) acc1[mt][nt] = mfma16(af[mt], bw, acc1[mt][nt]);
    }
  }
  for (int nt = 0; nt < 4; ++nt){
    int n = (wave*4 + nt)*16 + nl;
    float bias = b1s[n];
    for (int mt = 0; mt < 4; ++mt)
      for (int r = 0; r < 4; ++r){
        float v = acc1[mt][nt][r] + bias;
        u1[mt*16 + quad*4 + r][n] = f2bf(v > 0.0f ? v : 0.0f);
      }
  }
  __syncthreads();

  // layer 2: M=64, N=128, K=256
  fvec4 acc2[4][2];
  for (int a = 0; a < 4; ++a) for (int b = 0; b < 2; ++b) acc2[a][b] = (fvec4)0.0f;
  for (int ks = 0; ks < 8; ++ks){
    bvec8 af[4];
    for (int mt = 0; mt < 4; ++mt)
      af[mt] = *(const bvec8*)(&u1[mt*16 + nl][ks*32 + quad*8]);
    for (int nt = 0; nt < 2; ++nt){
      int n = (wave*2 + nt)*16 + nl;
      bvec8 bw = *(const bvec8*)(W2 + n*HID + ks*32 + quad*8);
      for (int mt = 0; mt < 4; ++mt) acc2[mt][nt] = mfma16(af[mt], bw, acc2[mt][nt]);
    }
  }
  for (int nt = 0; nt < 2; ++nt){
    int n = (wave*2 + nt)*16 + nl;
    float bias = b2s[n];
    for (int mt = 0; mt < 4; ++mt)
      for (int r = 0; r < 4; ++r){
        int b = mb*64 + mt*16 + quad*4 + r;
        size_t row = (size_t)t*BB + b;
        float v = acc2[mt][nt][r] + bias;
        if (p) recons[row*OBS + n] = v;
        else if (n < LAT) prior_mean[row*LAT + n] = v;
        else              prior_logvar[row*LAT + (n - LAT)] = v;
      }
  }
}

extern "C" void kernel_launch(void* const* d_in, const int* in_sizes, int n_in,
                              void* d_out, int out_size, void* d_ws, size_t ws_size,
                              hipStream_t stream) {
  const float* x    = (const float*)d_in[0];
  const float* eps  = (const float*)d_in[1];
  const float* W_ih = (const float*)d_in[2];
  const float* W_hh = (const float*)d_in[3];
  const float* b_ih = (const float*)d_in[4];
  const float* b_hh = (const float*)d_in[5];
  const float* tW1  = (const float*)d_in[6];
  const float* tb1  = (const float*)d_in[7];
  const float* tW2  = (const float*)d_in[8];
  const float* tb2  = (const float*)d_in[9];
  const float* pW1  = (const float*)d_in[10];
  const float* pb1  = (const float*)d_in[11];
  const float* pW2  = (const float*)d_in[12];
  const float* pb2  = (const float*)d_in[13];
  const float* dW1  = (const float*)d_in[14];
  const float* db1  = (const float*)d_in[15];
  const float* dW2  = (const float*)d_in[16];
  const float* db2  = (const float*)d_in[17];

  float* out          = (float*)d_out;
  float* recons       = out;                 // 512*256*128
  float* prior_mean   = out + 16777216;      // 512*256*64
  float* prior_logvar = out + 25165824;
  float* post_mean    = out + 33554432;
  float* post_logvar  = out + 41943040;

  char* ws = (char*)d_ws;
  short* h_all = (short*)ws;                         // 512*256*256 bf16 = 67,108,864 B
  short* z_all = (short*)(ws + 67108864);            // 512*256*64  bf16 = 16,777,216 B
  short* wts   = (short*)(ws + 67108864 + 16777216);
  short* Pw1 = wts;                  // 81920
  short* Pw2 = Pw1 + 81920;          // 32768
  short* Tw1 = Pw2 + 32768;          // 16384
  short* Tw2 = Tw1 + 16384;          // 32768
  short* Dw1 = Tw2 + 32768;          // 16384
  short* Dw2 = Dw1 + 16384;          // 32768

  cvt_kernel<<<(81920+255)/256, 256, 0, stream>>>(pW1, Pw1, 81920);
  cvt_kernel<<<(32768+255)/256, 256, 0, stream>>>(pW2, Pw2, 32768);
  cvt_kernel<<<(16384+255)/256, 256, 0, stream>>>(tW1, Tw1, 16384);
  cvt_kernel<<<(32768+255)/256, 256, 0, stream>>>(tW2, Tw2, 32768);
  cvt_kernel<<<(16384+255)/256, 256, 0, stream>>>(dW1, Dw1, 16384);
  cvt_kernel<<<(32768+255)/256, 256, 0, stream>>>(dW2, Dw2, 32768);

  gru_kernel<<<16, 512, 0, stream>>>(x, W_ih, W_hh, b_ih, b_hh, h_all);
  zscan_kernel<<<16, 256, 0, stream>>>(h_all, eps, Pw1, Pw2, pb1, pb2,
                                       z_all, post_mean, post_logvar);
  tail_kernel<<<4096, 256, 0, stream>>>(z_all, Tw1, Tw2, Dw1, Dw2,
                                        tb1, tb2, db1, db2,
                                        prior_mean, prior_logvar, recons);
}